// Round 2
// baseline (1448.654 us; speedup 1.0000x reference)
//
#include <hip/hip_runtime.h>
#include <stdint.h>

#define HW 3136
#define Wd 56
#define Cc 256
#define CH 64
#define Tt 8
#define Bb 8
#define NPART 13   // grid.x of k3/k4 px-blocks (13*256px = 3328 >= 3136)

typedef unsigned short ushort_t;
typedef __attribute__((ext_vector_type(2))) unsigned short us2;
typedef __attribute__((ext_vector_type(4))) unsigned short us4;
typedef __attribute__((ext_vector_type(4))) float f4;
typedef __attribute__((ext_vector_type(2))) float f2;

__device__ __forceinline__ float bf2f(ushort_t u) {
    union { unsigned int i; float f; } v;
    v.i = ((unsigned int)u) << 16;
    return v.f;
}
__device__ __forceinline__ ushort_t f2bf(float f) {
    union { float f; unsigned int i; } v;
    v.f = f;
    unsigned int r = (v.i + 0x7FFFu + ((v.i >> 16) & 1u)) >> 16;
    return (ushort_t)r;
}

// ---------------- K1: channel max/mean pooling ----------------
// grid 196, block 256. thread = 4 consecutive pixels, loop over 256 channels.
__global__ __launch_bounds__(256) void k1_pool(const float* __restrict__ x,
                                               float* __restrict__ pooled) {
    int u = blockIdx.x * 256 + threadIdx.x;      // 50176 = 64 bt * 784 px4
    int px4 = u % 784, bt = u / 784;
    long base = (long)bt * Cc * HW + px4 * 4;
    float mx[4], sm[4];
#pragma unroll
    for (int j = 0; j < 4; j++) { mx[j] = -3.4e38f; sm[j] = 0.f; }
    for (int c = 0; c < Cc; c++) {
        f4 xv = *(const f4*)(x + base + (long)c * HW);
#pragma unroll
        for (int j = 0; j < 4; j++) {
            mx[j] = fmaxf(mx[j], xv[j]);
            sm[j] += xv[j];
        }
    }
    f4 pm, pa;
#pragma unroll
    for (int j = 0; j < 4; j++) { pm[j] = mx[j]; pa[j] = sm[j] * (1.f / 256.f); }
    *(f4*)(pooled + (long)bt * 2 * HW + px4 * 4) = pm;
    *(f4*)(pooled + (long)bt * 2 * HW + HW + px4 * 4) = pa;
}

// ---------------- K2: 7x7 2ch conv + sigmoid gate ----------------
// grid 64 (one per bt image), block 256.
__global__ __launch_bounds__(256) void k2_conv(const float* __restrict__ pooled,
                                               const float* __restrict__ wsp,
                                               float* __restrict__ gate) {
    __shared__ float img[2 * HW];
    __shared__ float wf[98];
    int bt = blockIdx.x, tid = threadIdx.x;
    const float* src = pooled + (long)bt * 2 * HW;
    for (int i = tid; i < 2 * HW; i += 256) img[i] = src[i];
    if (tid < 98) wf[tid] = wsp[tid];
    __syncthreads();
    for (int p = tid; p < HW; p += 256) {
        int y = p / Wd, xx = p % Wd;
        float acc = 0.f;
        for (int ci = 0; ci < 2; ci++)
            for (int ky = 0; ky < 7; ky++) {
                int yy = y + ky - 3;
                if (yy < 0 || yy >= Wd) continue;
                for (int kx = 0; kx < 7; kx++) {
                    int xc = xx + kx - 3;
                    if (xc < 0 || xc >= Wd) continue;
                    acc += wf[ci * 49 + ky * 7 + kx] * img[ci * HW + yy * Wd + xc];
                }
            }
        gate[(long)bt * HW + p] = 1.f + 1.f / (1.f + __expf(-acc));
    }
}

// ---------------- K3: temporal reduce conv (GEMM 256 -> 64o x 3dt) + BN + relu ----------------
// grid (13, 64 bt, 2), block (64,4). thread = 4 px x 8 o.
__global__ __launch_bounds__(256) void k3_reduce(
    const float* __restrict__ x, const float* __restrict__ gate,
    const float* __restrict__ wr, const float* __restrict__ bng,
    const float* __restrict__ bnb, const float* __restrict__ bnm,
    const float* __restrict__ bnv, ushort_t* __restrict__ trelu) {
    int tx = threadIdx.x, ty = threadIdx.y;
    int bt = blockIdx.y;
    int b = bt >> 3, t = bt & 7;
    int px = (blockIdx.x * 64 + tx) * 4;
    bool act = px < HW;
    int o0 = blockIdx.z * 32 + ty * 8;

    float g[3][4];
    bool tv[3];
#pragma unroll
    for (int dt = 0; dt < 3; dt++) {
        int tp = t + dt - 1;
        tv[dt] = (tp >= 0 && tp < Tt);
#pragma unroll
        for (int j = 0; j < 4; j++) g[dt][j] = 0.f;
        if (tv[dt] && act) {
            f4 gv = *(const f4*)(gate + (long)(b * Tt + tp) * HW + px);
#pragma unroll
            for (int j = 0; j < 4; j++) g[dt][j] = gv[j];
        }
    }

    float acc[8][4];
#pragma unroll
    for (int oi = 0; oi < 8; oi++)
#pragma unroll
        for (int j = 0; j < 4; j++) acc[oi][j] = 0.f;

    if (act) {
        for (int c = 0; c < Cc; c++) {
            float xg[3][4];
#pragma unroll
            for (int dt = 0; dt < 3; dt++) {
                if (tv[dt]) {
                    int tp = t + dt - 1;
                    f4 xv = *(const f4*)(x + ((long)(b * Tt + tp) * Cc + c) * HW + px);
#pragma unroll
                    for (int j = 0; j < 4; j++) xg[dt][j] = xv[j] * g[dt][j];
                } else {
#pragma unroll
                    for (int j = 0; j < 4; j++) xg[dt][j] = 0.f;
                }
            }
            const float* wp = wr + ((long)o0 * Cc + c) * 3;
#pragma unroll
            for (int oi = 0; oi < 8; oi++) {
                float w0 = wp[oi * 768 + 0];
                float w1 = wp[oi * 768 + 1];
                float w2 = wp[oi * 768 + 2];
#pragma unroll
                for (int j = 0; j < 4; j++)
                    acc[oi][j] += w0 * xg[0][j] + w1 * xg[1][j] + w2 * xg[2][j];
            }
        }
#pragma unroll
        for (int oi = 0; oi < 8; oi++) {
            int o = o0 + oi;
            float inv = bng[o] * rsqrtf(bnv[o] + 1e-5f);
            float sh = bnb[o] - bnm[o] * inv;
            us4 st;
#pragma unroll
            for (int j = 0; j < 4; j++) {
                float v = acc[oi][j] * inv + sh;
                st[j] = f2bf(fmaxf(v, 0.f));
            }
            *(us4*)(trelu + ((long)(b * CH + o) * Tt + t) * HW + px) = st;
        }
    }
}

// ---------------- K4: expand GEMM (64->256) + sigmoid + x_t + spatial-sum partials ----------------
// grid (13, 64 bt, 16 c-groups), block (64,4). thread = 4 px x 4 c.
__global__ __launch_bounds__(256) void k4_expand(
    const float* __restrict__ x, const float* __restrict__ gate,
    const ushort_t* __restrict__ trelu, const float* __restrict__ we,
    ushort_t* __restrict__ xt, float* __restrict__ vpart) {
    int tx = threadIdx.x, ty = threadIdx.y;
    int bt = blockIdx.y;
    int b = bt >> 3, t = bt & 7;
    int px = (blockIdx.x * 64 + tx) * 4;
    bool act = px < HW;
    int c0 = blockIdx.z * 16 + ty * 4;

    float acc[4][4];
#pragma unroll
    for (int ci = 0; ci < 4; ci++)
#pragma unroll
        for (int j = 0; j < 4; j++) acc[ci][j] = 0.f;

    if (act) {
        for (int o = 0; o < CH; o++) {
            us4 tvv = *(const us4*)(trelu + ((long)(b * CH + o) * Tt + t) * HW + px);
            float tf[4];
#pragma unroll
            for (int j = 0; j < 4; j++) tf[j] = bf2f(tvv[j]);
#pragma unroll
            for (int ci = 0; ci < 4; ci++) {
                float w = we[(long)(c0 + ci) * CH + o];
#pragma unroll
                for (int j = 0; j < 4; j++) acc[ci][j] += w * tf[j];
            }
        }
    }

    float gg[4];
#pragma unroll
    for (int j = 0; j < 4; j++) gg[j] = 0.f;
    if (act) {
        f4 gv = *(const f4*)(gate + (long)bt * HW + px);
#pragma unroll
        for (int j = 0; j < 4; j++) gg[j] = gv[j];
    }

    float csum[4];
#pragma unroll
    for (int ci = 0; ci < 4; ci++) {
        float s = 0.f;
        if (act) {
            int c = c0 + ci;
            f4 xv = *(const f4*)(x + ((long)bt * Cc + c) * HW + px);
            us4 st;
#pragma unroll
            for (int j = 0; j < 4; j++) {
                float attn = 1.f / (1.f + __expf(-acc[ci][j]));
                float v = xv[j] * gg[j] * (1.f + attn);
                st[j] = f2bf(v);
                s += v;
            }
            *(us4*)(xt + ((long)(b * Cc + c) * Tt + t) * HW + px) = st;
        }
        csum[ci] = s;
    }

    // each ty row is one wave (tx 0..63): shuffle-reduce over tx
#pragma unroll
    for (int ci = 0; ci < 4; ci++) {
        float s = csum[ci];
        for (int off = 32; off > 0; off >>= 1) s += __shfl_down(s, off);
        if (tx == 0)
            vpart[((long)(b * Cc + (c0 + ci)) * Tt + t) * NPART + blockIdx.x] = s;
    }
}

// ---------------- K5: dynamic temporal kernel (fc1->relu->fc2->softmax) ----------------
// grid 8, block 256: thread per (b,c)
__global__ __launch_bounds__(256) void k5_dyn(
    const float* __restrict__ vpart, const float* __restrict__ wfc1,
    const float* __restrict__ bfc1, const float* __restrict__ wfc2,
    const float* __restrict__ bfc2, float* __restrict__ dk) {
    int u = blockIdx.x * 256 + threadIdx.x;   // 2048 = B*C
    int b = u >> 8, c = u & 255;
    float v[8];
#pragma unroll
    for (int t = 0; t < 8; t++) {
        float s = 0.f;
        for (int i = 0; i < NPART; i++)
            s += vpart[((long)(b * Cc + c) * Tt + t) * NPART + i];
        v[t] = s * (1.f / 3136.f);
    }
    float h[16];
#pragma unroll
    for (int j = 0; j < 16; j++) {
        float s = bfc1[j];
        for (int t = 0; t < 8; t++) s += wfc1[j * 8 + t] * v[t];
        h[j] = fmaxf(s, 0.f);
    }
    float l[3];
#pragma unroll
    for (int k = 0; k < 3; k++) {
        float s = bfc2[k];
        for (int j = 0; j < 16; j++) s += wfc2[k * 16 + j] * h[j];
        l[k] = s;
    }
    float m = fmaxf(l[0], fmaxf(l[1], l[2]));
    float e0 = __expf(l[0] - m), e1 = __expf(l[1] - m), e2 = __expf(l[2] - m);
    float inv = 1.f / (e0 + e1 + e2);
    dk[(long)u * 3 + 0] = e0 * inv;
    dk[(long)u * 3 + 1] = e1 * inv;
    dk[(long)u * 3 + 2] = e2 * inv;
}

// ---------------- K6: depthwise temporal 3-tap stencil ----------------
// grid (7, 256 c, 8 b), block 256: thread = 2 px, all 8 t in registers
__global__ __launch_bounds__(256) void k6_stencil(
    const ushort_t* __restrict__ xt, const float* __restrict__ dk,
    float* __restrict__ out) {
    int tx = threadIdx.x;
    int c = blockIdx.y, b = blockIdx.z;
    int px = (blockIdx.x * 256 + tx) * 2;
    if (px >= HW) return;
    const float* kk = dk + (long)(b * Cc + c) * 3;
    float k0 = kk[0], k1 = kk[1], k2 = kk[2];
    float pa[Tt][2];
    const ushort_t* src = xt + (long)(b * Cc + c) * Tt * HW + px;
#pragma unroll
    for (int t = 0; t < Tt; t++) {
        us2 xv = *(const us2*)(src + (long)t * HW);
        pa[t][0] = bf2f(xv[0]);
        pa[t][1] = bf2f(xv[1]);
    }
#pragma unroll
    for (int t = 0; t < Tt; t++) {
        float am = (t > 0) ? pa[t - 1][0] : 0.f, bm = (t > 0) ? pa[t - 1][1] : 0.f;
        float ap = (t < 7) ? pa[t + 1][0] : 0.f, bp = (t < 7) ? pa[t + 1][1] : 0.f;
        f2 r;
        r[0] = k0 * am + k1 * pa[t][0] + k2 * ap;
        r[1] = k0 * bm + k1 * pa[t][1] + k2 * bp;
        *(f2*)(out + ((long)(b * Tt + t) * Cc + c) * HW + px) = r;
    }
}

extern "C" void kernel_launch(void* const* d_in, const int* in_sizes, int n_in,
                              void* d_out, int out_size, void* d_ws, size_t ws_size,
                              hipStream_t stream) {
    const float* x    = (const float*)d_in[0];
    const float* wsp  = (const float*)d_in[1];
    const float* wr   = (const float*)d_in[2];
    const float* bng  = (const float*)d_in[3];
    const float* bnb  = (const float*)d_in[4];
    const float* bnm  = (const float*)d_in[5];
    const float* bnv  = (const float*)d_in[6];
    const float* we   = (const float*)d_in[7];
    const float* wfc1 = (const float*)d_in[8];
    const float* bfc1 = (const float*)d_in[9];
    const float* wfc2 = (const float*)d_in[10];
    const float* bfc2 = (const float*)d_in[11];
    float* out = (float*)d_out;

    char* ws = (char*)d_ws;
    size_t off = 0;
    float* pooled = (float*)(ws + off); off += (size_t)64 * 2 * HW * 4;            // 1.6 MB
    float* gate   = (float*)(ws + off); off += (size_t)64 * HW * 4;                // 0.8 MB
    ushort_t* trelu = (ushort_t*)(ws + off); off += (size_t)Bb * CH * Tt * HW * 2; // 25.7 MB
    ushort_t* xt    = (ushort_t*)(ws + off); off += (size_t)Bb * Cc * Tt * HW * 2; // 102.8 MB
    float* vpart  = (float*)(ws + off); off += (size_t)Bb * Cc * Tt * NPART * 4;   // 0.9 MB
    float* dk     = (float*)(ws + off); off += (size_t)Bb * Cc * 3 * 4;            // 24 KB

    hipLaunchKernelGGL(k1_pool, dim3(196), dim3(256), 0, stream, x, pooled);
    hipLaunchKernelGGL(k2_conv, dim3(64), dim3(256), 0, stream, pooled, wsp, gate);
    hipLaunchKernelGGL(k3_reduce, dim3(NPART, 64, 2), dim3(64, 4), 0, stream,
                       x, gate, wr, bng, bnb, bnm, bnv, trelu);
    hipLaunchKernelGGL(k4_expand, dim3(NPART, 64, 16), dim3(64, 4), 0, stream,
                       x, gate, trelu, we, xt, vpart);
    hipLaunchKernelGGL(k5_dyn, dim3(8), dim3(256), 0, stream,
                       vpart, wfc1, bfc1, wfc2, bfc2, dk);
    hipLaunchKernelGGL(k6_stencil, dim3(7, 256, 8), dim3(256), 0, stream, xt, dk, out);
}